// Round 10
// baseline (760.251 us; speedup 1.0000x reference)
//
#include <hip/hip_runtime.h>
#include <stdint.h>

#define DIN   64
#define HDIM  64
#define EIN   16
#define EHID  128     // edge hidden width
#define HH    4096    // HDIM*HDIM
#define TC    8256    // BmatT rows: 8192 main + 64 bias
#define STEPS 3

typedef short bf16x8 __attribute__((ext_vector_type(8)));
typedef float f32x4  __attribute__((ext_vector_type(4)));

__device__ __forceinline__ unsigned short f32_to_bf16(float f) {
    union { float f; uint32_t u; } v; v.f = f;
    uint32_t r = v.u + 0x7fffu + ((v.u >> 16) & 1u);   // RNE
    return (unsigned short)(r >> 16);
}
__device__ __forceinline__ float bfu_to_f(unsigned short u) {
    union { uint32_t u; float f; } v; v.u = (uint32_t)u << 16; return v.f;
}

// ---- merged prologue: [0,nbN) node_mlp | [nbN,+nbE) edge_mlp(MFMA) | [+nbB) bmat | rest hist ----
__global__ void k_pro(const float* __restrict__ nf, const float* __restrict__ W0,
                      const float* __restrict__ b0, float* __restrict__ outb,
                      unsigned short* __restrict__ outbf,
                      const float* __restrict__ ef, const float* __restrict__ We1,
                      const float* __restrict__ be1, unsigned short* __restrict__ h,
                      const float* __restrict__ We2, const float* __restrict__ be2,
                      unsigned short* __restrict__ BmatT,
                      const int* __restrict__ src, const int* __restrict__ dst,
                      int* __restrict__ cntS, int* __restrict__ cntD,
                      int n_nodes, int n_edges, int nbN, int nbE, int nbB) {
    __shared__ float smem[DIN * HDIM];   // 16 KB (node path only)
    int b = blockIdx.x, tid = threadIdx.x;
    if (b < nbN) {
        // node MLP: out[n,o] = relu(n_feat[n,:]@W0[:,o]+b0[o]); 4 nodes/block
        for (int i = tid; i < DIN * HDIM; i += 256) smem[i] = W0[i];
        __syncthreads();
        int node = b * 4 + (tid >> 6);
        int o = tid & 63;
        if (node >= n_nodes) return;
        float xr = nf[node * DIN + o];
        float acc = b0[o];
#pragma unroll 8
        for (int i = 0; i < DIN; ++i)
            acc += __shfl(xr, i, 64) * smem[i * HDIM + o];
        float v = fmaxf(acc, 0.f);
        outb[node * HDIM + o] = v;
        outbf[node * HDIM + o] = f32_to_bf16(v);
    } else if (b < nbN + nbE) {
        // edge MLP via MFMA: 64 edges/block (16/wave), K=16 zero-padded to 32.
        // h stored with per-64-group col perm sigma (inverse baked into BmatT K-index).
        int wave = tid >> 6, lane = tid & 63;
        int r = lane & 15, q = lane >> 4;
        int e0 = (b - nbN) * 64 + wave * 16;
        if (e0 >= n_edges) return;           // wave-uniform
        bf16x8 afr = (bf16x8){};
        bf16x8 bfr[8];
#pragma unroll
        for (int nt = 0; nt < 8; ++nt) bfr[nt] = (bf16x8){};
        if (q < 2) {
            int ea = e0 + r; if (ea >= n_edges) ea = n_edges - 1;
            const float* xa = ef + (size_t)ea * EIN + q * 8;
#pragma unroll
            for (int j = 0; j < 8; ++j) afr[j] = (short)f32_to_bf16(xa[j]);
#pragma unroll
            for (int nt = 0; nt < 8; ++nt)
#pragma unroll
                for (int j = 0; j < 8; ++j)
                    bfr[nt][j] = (short)f32_to_bf16(We1[(q * 8 + j) * EHID + nt * 16 + r]);
        }
        f32x4 acc[8];
#pragma unroll
        for (int nt = 0; nt < 8; ++nt)
            acc[nt] = __builtin_amdgcn_mfma_f32_16x16x32_bf16(afr, bfr[nt], (f32x4){}, 0, 0, 0);
        float bias[8];
#pragma unroll
        for (int nt = 0; nt < 8; ++nt) bias[nt] = be1[nt * 16 + r];
#pragma unroll
        for (int rg = 0; rg < 4; ++rg) {
            int e = e0 + q * 4 + rg;         // C/D: col=lane&15, row=quad*4+reg
            if (e >= n_edges) continue;
            ushort4 pk0, pk1;
            pk0.x = f32_to_bf16(fmaxf(acc[0][rg] + bias[0], 0.f));
            pk0.y = f32_to_bf16(fmaxf(acc[1][rg] + bias[1], 0.f));
            pk0.z = f32_to_bf16(fmaxf(acc[2][rg] + bias[2], 0.f));
            pk0.w = f32_to_bf16(fmaxf(acc[3][rg] + bias[3], 0.f));
            pk1.x = f32_to_bf16(fmaxf(acc[4][rg] + bias[4], 0.f));
            pk1.y = f32_to_bf16(fmaxf(acc[5][rg] + bias[5], 0.f));
            pk1.z = f32_to_bf16(fmaxf(acc[6][rg] + bias[6], 0.f));
            pk1.w = f32_to_bf16(fmaxf(acc[7][rg] + bias[7], 0.f));
            *(ushort4*)(h + (size_t)e * EHID + 4 * r) = pk0;
            *(ushort4*)(h + (size_t)e * EHID + 64 + 4 * r) = pk1;
        }
    } else if (b < nbN + nbE + nbB) {
        // BmatT for the FUSED kernel (R1 layout), generated with COALESCED We2
        // reads (iterate We2 linearly, scatter 2B writes; inverse verified).
        // Forward (row m=o*128+nt*16+r1, col i): K=r1*8+nt;
        //   k=(K&64)+((K&3)<<4)+((K>>2)&15); v=We2[k*4096+i*64+o].
        // Inverse (k,i,o -> m): K=(k&64)|((k&15)<<2)|((k>>4)&3);
        //   m=o*128+(K&7)*16+(K>>3).
        // Bias rows 8192+o, col i = be2[i*64+o].
        int t = (b - nbN - nbE) * 256 + tid;
        if (t >= TC * 64) return;            // 128*4096 + 4096
        if (t < (1 << 19)) {
            int k = t >> 12, i = (t >> 6) & 63, o = t & 63;
            int K = (k & 64) | ((k & 15) << 2) | ((k >> 4) & 3);
            int m = o * 128 + (K & 7) * 16 + (K >> 3);
            BmatT[m * 64 + i] = f32_to_bf16(We2[t]);
        } else {
            int t2 = t - (1 << 19);
            int i = t2 >> 6, o = t2 & 63;
            BmatT[(8192 + o) * 64 + i] = f32_to_bf16(be2[t2]);
        }
    } else {
        // histogram src and dst
        int e = (b - nbN - nbE - nbB) * 256 + tid;
        if (e >= n_edges) return;
        atomicAdd(&cntS[src[e]], 1);
        atomicAdd(&cntD[dst[e]], 1);
    }
}

// Fused T+msg, attempt #3 = R1's proven-correct kernel + ONE perf change:
// phase-1 batches all 16 B-loads of an og-iteration into registers BEFORE the
// MFMAs (R1's counters showed VGPR=52 -> loads serialized at ~200cyc each,
// 625MB B-stream at 3.5 TB/s = the 178us). __launch_bounds__(256,2) gives the
// register budget. Extras: chunk order staggered by blockIdx (L2 spread);
// msg written bf16 PLAIN-col at dst-rank (k_agg reads sequentially).
// Block = 16 src nodes, 4 o-chunks of 16 cols; T chunk lives in 64KB LDS
// (XOR-swizzled 16B slots), never touches HBM.
__global__ __launch_bounds__(256, 2)
void k_fused(const unsigned short* __restrict__ outbf,
             const unsigned short* __restrict__ BmatT,
             const unsigned short* __restrict__ h,
             const int* __restrict__ offS, const int* __restrict__ permS,
             const int* __restrict__ rankD,
             unsigned short* __restrict__ msg, int n_nodes) {
    __shared__ short Tlds[16 * 2048];   // 64 KB: node(4KB) x o_in(256B) x slot(16B)
    __shared__ float Tb[16 * 64];       // 4 KB bias
    int wave = threadIdx.x >> 6, lane = threadIdx.x & 63;
    int r = lane & 15, q = lane >> 4;
    int n0 = blockIdx.x * 16;
    int bid = blockIdx.x;

    // A fragments (16 nodes, row r = node n0+r), reused all chunks
    int na = n0 + r; if (na >= n_nodes) na = n_nodes - 1;
    bf16x8 afr0 = *(const bf16x8*)(outbf + (size_t)na * 64 + q * 8);
    bf16x8 afr1 = *(const bf16x8*)(outbf + (size_t)na * 64 + 32 + q * 8);

    // bias tile: wave covers o = wave*16 + r (all 64 cols over 4 waves)
    {
        size_t cofs = (size_t)(8192 + wave * 16 + r) * 64;
        bf16x8 bb0 = *(const bf16x8*)(BmatT + cofs + q * 8);
        bf16x8 bb1 = *(const bf16x8*)(BmatT + cofs + 32 + q * 8);
        f32x4 accB = __builtin_amdgcn_mfma_f32_16x16x32_bf16(afr0, bb0, (f32x4){}, 0, 0, 0);
        accB = __builtin_amdgcn_mfma_f32_16x16x32_bf16(afr1, bb1, accB, 0, 0, 0);
#pragma unroll
        for (int rg = 0; rg < 4; ++rg)
            Tb[(q * 4 + rg) * 64 + wave * 16 + r] = accB[rg];
    }

    int nlim = n_nodes - n0; if (nlim > 16) nlim = 16;

    for (int oc = 0; oc < 4; ++oc) {
        int ocp = (oc + bid) & 3;
        __syncthreads();   // prev phase-2 done reading Tlds (first iter: Tb ready)
        // ---- phase 1: T chunk ocp -> LDS; per og: 16 loads BATCHED, then MFMAs
#pragma unroll 1
        for (int og = 0; og < 4; ++og) {
            int o_in = wave * 4 + og;
            bf16x8 bv0[8], bv1[8];
#pragma unroll
            for (int nt = 0; nt < 8; ++nt) {
                size_t cofs = (size_t)(ocp * 2048 + (o_in * 8 + nt) * 16 + r) * 64;
                bv0[nt] = *(const bf16x8*)(BmatT + cofs + q * 8);
                bv1[nt] = *(const bf16x8*)(BmatT + cofs + 32 + q * 8);
            }
            f32x4 a8[8];
#pragma unroll
            for (int nt = 0; nt < 8; ++nt) {
                a8[nt] = __builtin_amdgcn_mfma_f32_16x16x32_bf16(afr0, bv0[nt], (f32x4){}, 0, 0, 0);
                a8[nt] = __builtin_amdgcn_mfma_f32_16x16x32_bf16(afr1, bv1[nt], a8[nt], 0, 0, 0);
            }
            // lane holds (node=q*4+rg, o_in, K=r*8+nt); pack nt -> one 16B slot
#pragma unroll
            for (int rg = 0; rg < 4; ++rg) {
                bf16x8 pk;
#pragma unroll
                for (int nt = 0; nt < 8; ++nt)
                    pk[nt] = (short)f32_to_bf16(a8[nt][rg]);
                *(bf16x8*)((char*)Tlds + ((q * 4 + rg) << 12) + (o_in << 8)
                           + (((r ^ (o_in & 7)) & 15) << 4)) = pk;
            }
        }
        __syncthreads();
        // ---- phase 2: msg cols [ocp*16, +16) for this block's edges (R1 walk)
        int tt = 0;
        for (int ni = 0; ni < nlim; ++ni) {
            int beg = offS[n0 + ni], end = offS[n0 + ni + 1];
            for (int j0 = beg; j0 < end; j0 += 16, ++tt) {
                if ((tt & 3) != wave) continue;       // wave-uniform
                int jc = j0 + r; if (jc >= end) jc = end - 1;
                int e = permS[jc];
                const unsigned short* he = h + (size_t)e * EHID;
                f32x4 acc = {};
#pragma unroll
                for (int ks = 0; ks < 4; ++ks) {
                    bf16x8 afr = *(const bf16x8*)(he + ks * 32 + q * 8);
                    bf16x8 bfr = *(const bf16x8*)((char*)Tlds + (ni << 12) + (r << 8)
                                   + ((((ks * 4 + q) ^ (r & 7)) & 15) << 4));
                    acc = __builtin_amdgcn_mfma_f32_16x16x32_bf16(afr, bfr, acc, 0, 0, 0);
                }
                float bias = Tb[ni * 64 + ocp * 16 + r];
#pragma unroll
                for (int rg = 0; rg < 4; ++rg) {      // C/D: col=lane&15, row=q*4+rg
                    int jr = j0 + q * 4 + rg;
                    if (jr >= end) continue;
                    int er = permS[jr];
                    msg[(size_t)rankD[er] * 64 + ocp * 16 + r]
                        = f32_to_bf16(acc[rg] + bias);
                }
            }
        }
    }
}

// exclusive prefix sum (one block per array; blockIdx.x: 0=S, 1=D)
__global__ void k_scan(const int* __restrict__ cntS, const int* __restrict__ cntD,
                       int* __restrict__ offS, int* __restrict__ offD,
                       int* __restrict__ curS, int* __restrict__ curD, int n, int total) {
    const int* cnt = blockIdx.x ? cntD : cntS;
    int* off = blockIdx.x ? offD : offS;
    int* cur = blockIdx.x ? curD : curS;
    __shared__ int part[256];
    int tid = threadIdx.x;
    int chunk = (n + 255) / 256;
    int c0 = tid * chunk, c1 = c0 + chunk; if (c1 > n) c1 = n; if (c0 > n) c0 = n;
    int s = 0;
    for (int i = c0; i < c1; ++i) s += cnt[i];
    part[tid] = s;
    __syncthreads();
    for (int st = 1; st < 256; st <<= 1) {
        int v = (tid >= st) ? part[tid - st] : 0;
        __syncthreads();
        part[tid] += v;
        __syncthreads();
    }
    int run = tid ? part[tid - 1] : 0;
    for (int i = c0; i < c1; ++i) { off[i] = run; cur[i] = run; run += cnt[i]; }
    if (tid == 0) off[n] = total;
}

// perm + rank: permS for src grouping; rankD[e] = position of e in dst-sorted order
__global__ void k_perm(const int* __restrict__ src, const int* __restrict__ dst,
                       int* __restrict__ curS, int* __restrict__ curD,
                       int* __restrict__ permS, int* __restrict__ rankD, int n_edges) {
    int e = blockIdx.x * 256 + threadIdx.x;
    if (e >= n_edges) return;
    permS[atomicAdd(&curS[src[e]], 1)] = e;
    rankD[e] = atomicAdd(&curD[dst[e]], 1);
}

// one block per dst node; deg split over 4 waves + LDS reduce; msg sequential
// (dst-rank order) with PLAIN cols: o = lane.
__global__ void k_agg(const unsigned short* __restrict__ msg, const int* __restrict__ offD,
                      const float* __restrict__ cbias,
                      float* __restrict__ outb, unsigned short* __restrict__ outbf, int n_nodes) {
    __shared__ float red[4][64];
    int wave = threadIdx.x >> 6, lane = threadIdx.x & 63;
    int d = blockIdx.x;
    if (d >= n_nodes) return;
    int beg = offD[d], end = offD[d + 1];
    float acc = 0.f;
    for (int j = beg + wave; j < end; j += 4)
        acc += bfu_to_f(msg[(size_t)j * 64 + lane]);
    red[wave][lane] = acc;
    __syncthreads();
    if (wave == 0) {
        float v = red[0][lane] + red[1][lane] + red[2][lane] + red[3][lane];
        v = fmaxf(v + cbias[lane], 0.f);
        outb[(size_t)d * 64 + lane] = v;
        outbf[(size_t)d * 64 + lane] = f32_to_bf16(v);
    }
}

// grid MUST be 64 blocks (row stride 256 hardcoded)
__global__ void k_bn_stats(const float* __restrict__ out, float* __restrict__ stat, int n_nodes) {
    __shared__ float s1[256], s2[256];
    int tid = threadIdx.x;
    int f = tid & 63, g = tid >> 6;
    float sum = 0.f, ss = 0.f;
    for (int r = blockIdx.x * 4 + g; r < n_nodes; r += 256) {
        float v = out[r * HDIM + f];
        sum += v; ss += v * v;
    }
    s1[tid] = sum; s2[tid] = ss;
    __syncthreads();
    if (tid < 64) {
        float A = s1[tid] + s1[64 + tid] + s1[128 + tid] + s1[192 + tid];
        float B = s2[tid] + s2[64 + tid] + s2[128 + tid] + s2[192 + tid];
        atomicAdd(&stat[tid], A);
        atomicAdd(&stat[64 + tid], B);
    }
}

// bn_final fused in: every thread derives scale/shift from stat (identical arith)
__global__ void k_bn_apply(const float* __restrict__ out, const float* __restrict__ stat,
                           const float* __restrict__ gamma, const float* __restrict__ beta,
                           float* __restrict__ y, int n, int n_nodes) {
    int t = blockIdx.x * 256 + threadIdx.x;
    if (t >= n) return;
    int f = t & 63;
    float mean = stat[f] / n_nodes;
    float var  = stat[64 + f] / n_nodes - mean * mean;   // population var
    float inv  = rsqrtf(var + 1e-5f);
    float scale = gamma[f] * inv;
    float shift = beta[f] - mean * scale;
    y[t] = out[t] * scale + shift;
}

extern "C" void kernel_launch(void* const* d_in, const int* in_sizes, int n_in,
                              void* d_out, int out_size, void* d_ws, size_t ws_size,
                              hipStream_t stream) {
    const float* nf    = (const float*)d_in[0];
    const float* ef    = (const float*)d_in[1];
    const int*   src   = (const int*)d_in[2];
    const int*   dst   = (const int*)d_in[3];
    const float* W0    = (const float*)d_in[4];
    const float* b0    = (const float*)d_in[5];
    const float* We1   = (const float*)d_in[6];
    const float* be1   = (const float*)d_in[7];
    const float* We2   = (const float*)d_in[8];
    const float* be2   = (const float*)d_in[9];
    const float* cbias = (const float*)d_in[10];
    const float* gamma = (const float*)d_in[11];
    const float* beta  = (const float*)d_in[12];
    (void)n_in; (void)out_size; (void)ws_size;

    int n_nodes = in_sizes[0] / DIN;   // 10000
    int n_edges = in_sizes[2];         // 100000

    char* ws = (char*)d_ws;
    size_t off = 0;
    auto carve = [&](size_t bytes) -> void* {
        void* p = ws + off;
        off = (off + bytes + 255) & ~(size_t)255;
        return p;
    };
    unsigned short* h     = (unsigned short*)carve((size_t)n_edges * EHID * 2);  // 25.6 MB
    unsigned short* msg   = (unsigned short*)carve((size_t)n_edges * 64 * 2);    // 12.8 MB (bf16)
    float*          outb  = (float*)carve((size_t)n_nodes * HDIM * 4);
    unsigned short* outbf = (unsigned short*)carve((size_t)n_nodes * HDIM * 2);
    unsigned short* BmatT = (unsigned short*)carve((size_t)TC * 64 * 2);
    int*            offS  = (int*)carve((size_t)(n_nodes + 1) * 4);
    int*            offD  = (int*)carve((size_t)(n_nodes + 1) * 4);
    int*            curS  = (int*)carve((size_t)n_nodes * 4);
    int*            curD  = (int*)carve((size_t)n_nodes * 4);
    int*            permS = (int*)carve((size_t)n_edges * 4);
    int*            rankD = (int*)carve((size_t)n_edges * 4);
    float*          stat  = (float*)carve(128 * 4 + (size_t)2 * n_nodes * 4); // stat + cntS + cntD
    int*            cntS  = (int*)(stat + 128);
    int*            cntD  = cntS + n_nodes;

    hipMemsetAsync(stat, 0, 128 * 4 + (size_t)2 * n_nodes * 4, stream);

    int nbN = (n_nodes + 3) / 4;            // 2500
    int nbE = (n_edges + 63) / 64;          // 1563 (MFMA edge path: 64 edges/block)
    int nbB = (TC * 64 + 255) / 256;        // 2064
    int nbH = (n_edges + 255) / 256;        // 391
    k_pro<<<dim3(nbN + nbE + nbB + nbH), 256, 0, stream>>>(
        nf, W0, b0, outb, outbf, ef, We1, be1, h, We2, be2, BmatT,
        src, dst, cntS, cntD, n_nodes, n_edges, nbN, nbE, nbB);
    k_scan<<<dim3(2), 256, 0, stream>>>(cntS, cntD, offS, offD, curS, curD, n_nodes, n_edges);
    k_perm<<<dim3((n_edges + 255) / 256), 256, 0, stream>>>(src, dst, curS, curD, permS, rankD, n_edges);

    int nbF = (n_nodes + 15) / 16;          // 625 fused blocks
    for (int step = 0; step < STEPS; ++step) {
        k_fused<<<dim3(nbF), 256, 0, stream>>>(outbf, BmatT, h, offS, permS, rankD, msg, n_nodes);
        k_agg<<<dim3(n_nodes), 256, 0, stream>>>(msg, offD, cbias, outb, outbf, n_nodes);
    }

    k_bn_stats<<<dim3(64), 256, 0, stream>>>(outb, stat, n_nodes);
    k_bn_apply<<<dim3((n_nodes * HDIM + 255) / 256), 256, 0, stream>>>(
        outb, stat, gamma, beta, (float*)d_out, n_nodes * HDIM, n_nodes);
}

// Round 11
// 414.185 us; speedup vs baseline: 1.8355x; 1.8355x over previous
//
#include <hip/hip_runtime.h>
#include <stdint.h>

#define DIN   64
#define HDIM  64
#define EIN   16
#define EHID  128     // edge hidden width
#define HH    4096    // HDIM*HDIM
#define TC    8256    // T cols: 8192 main + 64 bias
#define STEPS 3

typedef short bf16x8 __attribute__((ext_vector_type(8)));
typedef float f32x4  __attribute__((ext_vector_type(4)));

__device__ __forceinline__ unsigned short f32_to_bf16(float f) {
    union { float f; uint32_t u; } v; v.f = f;
    uint32_t r = v.u + 0x7fffu + ((v.u >> 16) & 1u);   // RNE
    return (unsigned short)(r >> 16);
}
__device__ __forceinline__ float bfu_to_f(unsigned short u) {
    union { uint32_t u; float f; } v; v.u = (uint32_t)u << 16; return v.f;
}

// ---- merged prologue: [0,nbN) node_mlp | [nbN,+nbE) edge_mlp(MFMA) | [+nbB) bmat | rest hist ----
__global__ void k_pro(const float* __restrict__ nf, const float* __restrict__ W0,
                      const float* __restrict__ b0, float* __restrict__ outb,
                      unsigned short* __restrict__ outbf,
                      const float* __restrict__ ef, const float* __restrict__ We1,
                      const float* __restrict__ be1, unsigned short* __restrict__ h,
                      const float* __restrict__ We2, const float* __restrict__ be2,
                      unsigned short* __restrict__ BmatT,
                      const int* __restrict__ src, const int* __restrict__ dst,
                      int* __restrict__ cntS, int* __restrict__ cntD,
                      int n_nodes, int n_edges, int nbN, int nbE, int nbB) {
    __shared__ float smem[DIN * HDIM];   // 16 KB (node path only)
    int b = blockIdx.x, tid = threadIdx.x;
    if (b < nbN) {
        // node MLP: out[n,o] = relu(n_feat[n,:]@W0[:,o]+b0[o]); 4 nodes/block
        for (int i = tid; i < DIN * HDIM; i += 256) smem[i] = W0[i];
        __syncthreads();
        int node = b * 4 + (tid >> 6);
        int o = tid & 63;
        if (node >= n_nodes) return;
        float xr = nf[node * DIN + o];
        float acc = b0[o];
#pragma unroll 8
        for (int i = 0; i < DIN; ++i)
            acc += __shfl(xr, i, 64) * smem[i * HDIM + o];
        float v = fmaxf(acc, 0.f);
        outb[node * HDIM + o] = v;
        outbf[node * HDIM + o] = f32_to_bf16(v);
    } else if (b < nbN + nbE) {
        // edge MLP via MFMA: 64 edges/block (16/wave), K=16 zero-padded to 32.
        // h stored with per-64-group col perm sigma (inverse baked into BmatT k-index).
        int wave = tid >> 6, lane = tid & 63;
        int r = lane & 15, q = lane >> 4;
        int e0 = (b - nbN) * 64 + wave * 16;
        if (e0 >= n_edges) return;           // wave-uniform
        bf16x8 afr = (bf16x8){};
        bf16x8 bfr[8];
#pragma unroll
        for (int nt = 0; nt < 8; ++nt) bfr[nt] = (bf16x8){};
        if (q < 2) {
            int ea = e0 + r; if (ea >= n_edges) ea = n_edges - 1;
            const float* xa = ef + (size_t)ea * EIN + q * 8;
#pragma unroll
            for (int j = 0; j < 8; ++j) afr[j] = (short)f32_to_bf16(xa[j]);
#pragma unroll
            for (int nt = 0; nt < 8; ++nt)
#pragma unroll
                for (int j = 0; j < 8; ++j)
                    bfr[nt][j] = (short)f32_to_bf16(We1[(q * 8 + j) * EHID + nt * 16 + r]);
        }
        f32x4 acc[8];
#pragma unroll
        for (int nt = 0; nt < 8; ++nt)
            acc[nt] = __builtin_amdgcn_mfma_f32_16x16x32_bf16(afr, bfr[nt], (f32x4){}, 0, 0, 0);
        float bias[8];
#pragma unroll
        for (int nt = 0; nt < 8; ++nt) bias[nt] = be1[nt * 16 + r];
#pragma unroll
        for (int rg = 0; rg < 4; ++rg) {
            int e = e0 + q * 4 + rg;         // C/D: col=lane&15, row=quad*4+reg
            if (e >= n_edges) continue;
            ushort4 pk0, pk1;
            pk0.x = f32_to_bf16(fmaxf(acc[0][rg] + bias[0], 0.f));
            pk0.y = f32_to_bf16(fmaxf(acc[1][rg] + bias[1], 0.f));
            pk0.z = f32_to_bf16(fmaxf(acc[2][rg] + bias[2], 0.f));
            pk0.w = f32_to_bf16(fmaxf(acc[3][rg] + bias[3], 0.f));
            pk1.x = f32_to_bf16(fmaxf(acc[4][rg] + bias[4], 0.f));
            pk1.y = f32_to_bf16(fmaxf(acc[5][rg] + bias[5], 0.f));
            pk1.z = f32_to_bf16(fmaxf(acc[6][rg] + bias[6], 0.f));
            pk1.w = f32_to_bf16(fmaxf(acc[7][rg] + bias[7], 0.f));
            *(ushort4*)(h + (size_t)e * EHID + 4 * r) = pk0;
            *(ushort4*)(h + (size_t)e * EHID + 64 + 4 * r) = pk1;
        }
    } else if (b < nbN + nbE + nbB) {
        // BmatT build: COALESCED We2 read (iterate We2 linearly, scatter 2B
        // writes into the split-pipeline T'' layout via the verified inverse map).
        int t = (b - nbN - nbE) * 256 + tid;
        if (t >= TC * 64) return;            // 128*4096 + 4096
        if (t < 128 * 4096) {
            int k = t >> 12, j = t & 4095, i = j >> 6, o = j & 63;
            int p = (k & 64) | ((k & 15) << 2) | ((k >> 4) & 3);
            int m = ((p >> 5) << 11) | (o << 5) | (p & 31);
            int mb = m & 127;
            int c = (m & ~127) | ((mb & 7) << 4) | (mb >> 3);
            BmatT[c * 64 + i] = f32_to_bf16(We2[t]);
        } else {
            int t2 = t - 128 * 4096;         // bias: be2 read coalesced
            int i = t2 >> 6, col = t2 & 63;
            int c = 8192 + (((col & 3) << 4) | (col >> 2));
            BmatT[c * 64 + i] = f32_to_bf16(be2[t2]);
        }
    } else {
        // histogram src and dst
        int e = (b - nbN - nbE - nbB) * 256 + tid;
        if (e >= n_edges) return;
        atomicAdd(&cntS[src[e]], 1);
        atomicAdd(&cntD[dst[e]], 1);
    }
}

// T[n, m] = sum_i x[n,i]*B[i,m], bf16 out, panel-major (panel p = 512 cols,
// bias panel bf16 at 16*pstr), 64 nodes per y-block. k_T is at its measured
// floor (~43us, 4.1 TB/s mixed): six store-side variants (R0/R3/R5 layouts,
// launch-bounds R4, forced residency R6/R7, 2x blocks R8) all neutral-or-worse;
// fusion with k_msg tried 3x (R1/R2/R10), all ~2.5x worse per-step (latency-
// bound at 2 waves/SIMD behind phase barriers). This split form is the floor.
__global__ void k_T(const unsigned short* __restrict__ outbf, const unsigned short* __restrict__ BmatT,
                    unsigned short* __restrict__ T, int n0, int n1) {
    int wave = threadIdx.x >> 6, lane = threadIdx.x & 63;
    int r = lane & 15, q = lane >> 4;
    int eb = n0 + blockIdx.y * 64;
    size_t pstr = (size_t)(n1 - n0) * 512;   // ushorts per panel
    if (blockIdx.x < 16) {
        int cb = blockIdx.x * 512 + wave * 128;          // BmatT column base
        unsigned short* Tp = T + (size_t)blockIdx.x * pstr;
        bf16x8 bfr[8][2];
#pragma unroll
        for (int nt = 0; nt < 8; ++nt) {
            size_t cofs = (size_t)(cb + nt * 16 + r) * 64;
            bfr[nt][0] = *(const bf16x8*)(BmatT + cofs + q * 8);
            bfr[nt][1] = *(const bf16x8*)(BmatT + cofs + 32 + q * 8);
        }
#pragma unroll
        for (int mt = 0; mt < 4; ++mt) {
            int e = eb + mt * 16 + r;
            if (e >= n1) e = n1 - 1;
            bf16x8 afr0 = *(const bf16x8*)(outbf + (size_t)e * 64 + q * 8);
            bf16x8 afr1 = *(const bf16x8*)(outbf + (size_t)e * 64 + 32 + q * 8);
            f32x4 acc[8];
#pragma unroll
            for (int nt = 0; nt < 8; ++nt) {
                acc[nt] = __builtin_amdgcn_mfma_f32_16x16x32_bf16(afr0, bfr[nt][0], (f32x4){}, 0, 0, 0);
                acc[nt] = __builtin_amdgcn_mfma_f32_16x16x32_bf16(afr1, bfr[nt][1], acc[nt], 0, 0, 0);
            }
#pragma unroll
            for (int rg = 0; rg < 4; ++rg) {
                int n = eb + mt * 16 + q * 4 + rg;   // C/D: col=lane&15, row=quad*4+reg
                if (n >= n1) continue;
                ushort4 pa, pb;
                pa.x = f32_to_bf16(acc[0][rg]); pa.y = f32_to_bf16(acc[1][rg]);
                pa.z = f32_to_bf16(acc[2][rg]); pa.w = f32_to_bf16(acc[3][rg]);
                pb.x = f32_to_bf16(acc[4][rg]); pb.y = f32_to_bf16(acc[5][rg]);
                pb.z = f32_to_bf16(acc[6][rg]); pb.w = f32_to_bf16(acc[7][rg]);
                uint4 pk = { ((uint32_t)pa.y << 16) | pa.x, ((uint32_t)pa.w << 16) | pa.z,
                             ((uint32_t)pb.y << 16) | pb.x, ((uint32_t)pb.w << 16) | pb.z };
                *(uint4*)(Tp + (size_t)(n - n0) * 512 + wave * 128 + 8 * r) = pk;
            }
        }
    } else {
        if (wave != 0) return;               // bias tail: 64 cols, bf16 bias panel
        int cb = 8192;
        unsigned short* Tb16 = T + 16 * pstr;
        bf16x8 bfr[4][2];
#pragma unroll
        for (int nt = 0; nt < 4; ++nt) {
            size_t cofs = (size_t)(cb + nt * 16 + r) * 64;
            bfr[nt][0] = *(const bf16x8*)(BmatT + cofs + q * 8);
            bfr[nt][1] = *(const bf16x8*)(BmatT + cofs + 32 + q * 8);
        }
#pragma unroll
        for (int mt = 0; mt < 4; ++mt) {
            int e = eb + mt * 16 + r;
            if (e >= n1) e = n1 - 1;
            bf16x8 afr0 = *(const bf16x8*)(outbf + (size_t)e * 64 + q * 8);
            bf16x8 afr1 = *(const bf16x8*)(outbf + (size_t)e * 64 + 32 + q * 8);
            f32x4 acc[4];
#pragma unroll
            for (int nt = 0; nt < 4; ++nt) {
                acc[nt] = __builtin_amdgcn_mfma_f32_16x16x32_bf16(afr0, bfr[nt][0], (f32x4){}, 0, 0, 0);
                acc[nt] = __builtin_amdgcn_mfma_f32_16x16x32_bf16(afr1, bfr[nt][1], acc[nt], 0, 0, 0);
            }
#pragma unroll
            for (int rg = 0; rg < 4; ++rg) {
                int n = eb + mt * 16 + q * 4 + rg;
                if (n >= n1) continue;
                ushort4 pk;
                pk.x = f32_to_bf16(acc[0][rg]);
                pk.y = f32_to_bf16(acc[1][rg]);
                pk.z = f32_to_bf16(acc[2][rg]);
                pk.w = f32_to_bf16(acc[3][rg]);
                *(ushort4*)(Tb16 + (size_t)(n - n0) * 64 + 4 * r) = pk;
            }
        }
    }
}

// per src-node wave, MFMA: msg[tile of 16 edges][64 o] = h[edges, 0:128] @ T''[n]
// T is panel-major (see k_T). msg rows stored at the edge's DST-SORTED rank
// (rankD[e]) -> k_agg reads msg sequentially. msg cols permuted bf16:
// mem col 4r+nt holds mfma col nt*16+r.
__global__ void k_msg(const unsigned short* __restrict__ h, const unsigned short* __restrict__ T,
                      const int* __restrict__ offS, const int* __restrict__ permS,
                      const int* __restrict__ rankD,
                      unsigned short* __restrict__ msg, int n0, int n1) {
    int wave = threadIdx.x >> 6, lane = threadIdx.x & 63;
    int n = n0 + blockIdx.x * 4 + wave;
    if (n >= n1) return;
    int beg = offS[n], end = offS[n + 1];
    if (beg == end) return;
    int r = lane & 15, q = lane >> 4;
    size_t pstr = (size_t)(n1 - n0) * 512;
    const unsigned short* Tb = T + (size_t)(n - n0) * 512;
    float bias[4];
#pragma unroll
    for (int nt = 0; nt < 4; ++nt)
        bias[nt] = bfu_to_f(T[16 * pstr + (size_t)(n - n0) * 64 + nt * 16 + r]);
    for (int j0 = beg; j0 < end; j0 += 16) {
        int jc = j0 + r; if (jc >= end) jc = end - 1;
        int e = permS[jc];
        const unsigned short* he = h + (size_t)e * EHID;
        f32x4 acc[4] = {};
#pragma unroll
        for (int s = 0; s < 4; ++s) {        // K = 128 = 4*32
            bf16x8 afr = *(const bf16x8*)(he + s * 32 + q * 8);
#pragma unroll
            for (int nt = 0; nt < 4; ++nt) {
                bf16x8 bfr = *(const bf16x8*)(Tb + (size_t)(s * 4 + nt) * pstr + r * 32 + q * 8);
                acc[nt] = __builtin_amdgcn_mfma_f32_16x16x32_bf16(afr, bfr, acc[nt], 0, 0, 0);
            }
        }
#pragma unroll
        for (int rg = 0; rg < 4; ++rg) {
            int jr = j0 + q * 4 + rg;
            if (jr >= end) continue;
            int er = permS[jr];
            int rk = rankD[er];
            ushort4 pk;
            pk.x = f32_to_bf16(acc[0][rg] + bias[0]);
            pk.y = f32_to_bf16(acc[1][rg] + bias[1]);
            pk.z = f32_to_bf16(acc[2][rg] + bias[2]);
            pk.w = f32_to_bf16(acc[3][rg] + bias[3]);
            *(ushort4*)(msg + (size_t)rk * 64 + 4 * r) = pk;
        }
    }
}

// exclusive prefix sum (one block per array; blockIdx.x: 0=S, 1=D)
__global__ void k_scan(const int* __restrict__ cntS, const int* __restrict__ cntD,
                       int* __restrict__ offS, int* __restrict__ offD,
                       int* __restrict__ curS, int* __restrict__ curD, int n, int total) {
    const int* cnt = blockIdx.x ? cntD : cntS;
    int* off = blockIdx.x ? offD : offS;
    int* cur = blockIdx.x ? curD : curS;
    __shared__ int part[256];
    int tid = threadIdx.x;
    int chunk = (n + 255) / 256;
    int c0 = tid * chunk, c1 = c0 + chunk; if (c1 > n) c1 = n; if (c0 > n) c0 = n;
    int s = 0;
    for (int i = c0; i < c1; ++i) s += cnt[i];
    part[tid] = s;
    __syncthreads();
    for (int st = 1; st < 256; st <<= 1) {
        int v = (tid >= st) ? part[tid - st] : 0;
        __syncthreads();
        part[tid] += v;
        __syncthreads();
    }
    int run = tid ? part[tid - 1] : 0;
    for (int i = c0; i < c1; ++i) { off[i] = run; cur[i] = run; run += cnt[i]; }
    if (tid == 0) off[n] = total;
}

// perm + rank: permS for src grouping; rankD[e] = position of e in dst-sorted order
__global__ void k_perm(const int* __restrict__ src, const int* __restrict__ dst,
                       int* __restrict__ curS, int* __restrict__ curD,
                       int* __restrict__ permS, int* __restrict__ rankD, int n_edges) {
    int e = blockIdx.x * 256 + threadIdx.x;
    if (e >= n_edges) return;
    permS[atomicAdd(&curS[src[e]], 1)] = e;
    rankD[e] = atomicAdd(&curD[dst[e]], 1);
}

// one BLOCK per dst node; deg split over 4 waves + LDS reduce; msg sequential
// (dst-rank order); cols permuted: lane l -> o=(l&3)*16+(l>>2).
__global__ void k_agg(const unsigned short* __restrict__ msg, const int* __restrict__ offD,
                      const float* __restrict__ cbias,
                      float* __restrict__ outb, unsigned short* __restrict__ outbf, int n_nodes) {
    __shared__ float red[4][64];
    int wave = threadIdx.x >> 6, lane = threadIdx.x & 63;
    int d = blockIdx.x;
    if (d >= n_nodes) return;
    int beg = offD[d], end = offD[d + 1];
    float acc = 0.f;
    for (int j = beg + wave; j < end; j += 4)
        acc += bfu_to_f(msg[(size_t)j * 64 + lane]);
    red[wave][lane] = acc;
    __syncthreads();
    if (wave == 0) {
        int o = (lane & 3) * 16 + (lane >> 2);
        float v = red[0][lane] + red[1][lane] + red[2][lane] + red[3][lane];
        v = fmaxf(v + cbias[o], 0.f);
        outb[(size_t)d * 64 + o] = v;
        outbf[(size_t)d * 64 + o] = f32_to_bf16(v);
    }
}

// grid MUST be 64 blocks (row stride 256 hardcoded)
__global__ void k_bn_stats(const float* __restrict__ out, float* __restrict__ stat, int n_nodes) {
    __shared__ float s1[256], s2[256];
    int tid = threadIdx.x;
    int f = tid & 63, g = tid >> 6;
    float sum = 0.f, ss = 0.f;
    for (int r = blockIdx.x * 4 + g; r < n_nodes; r += 256) {
        float v = out[r * HDIM + f];
        sum += v; ss += v * v;
    }
    s1[tid] = sum; s2[tid] = ss;
    __syncthreads();
    if (tid < 64) {
        float A = s1[tid] + s1[64 + tid] + s1[128 + tid] + s1[192 + tid];
        float B = s2[tid] + s2[64 + tid] + s2[128 + tid] + s2[192 + tid];
        atomicAdd(&stat[tid], A);
        atomicAdd(&stat[64 + tid], B);
    }
}

// bn_final fused in: every thread derives scale/shift from stat (identical arith)
__global__ void k_bn_apply(const float* __restrict__ out, const float* __restrict__ stat,
                           const float* __restrict__ gamma, const float* __restrict__ beta,
                           float* __restrict__ y, int n, int n_nodes) {
    int t = blockIdx.x * 256 + threadIdx.x;
    if (t >= n) return;
    int f = t & 63;
    float mean = stat[f] / n_nodes;
    float var  = stat[64 + f] / n_nodes - mean * mean;   // population var
    float inv  = rsqrtf(var + 1e-5f);
    float scale = gamma[f] * inv;
    float shift = beta[f] - mean * scale;
    y[t] = out[t] * scale + shift;
}

extern "C" void kernel_launch(void* const* d_in, const int* in_sizes, int n_in,
                              void* d_out, int out_size, void* d_ws, size_t ws_size,
                              hipStream_t stream) {
    const float* nf    = (const float*)d_in[0];
    const float* ef    = (const float*)d_in[1];
    const int*   src   = (const int*)d_in[2];
    const int*   dst   = (const int*)d_in[3];
    const float* W0    = (const float*)d_in[4];
    const float* b0    = (const float*)d_in[5];
    const float* We1   = (const float*)d_in[6];
    const float* be1   = (const float*)d_in[7];
    const float* We2   = (const float*)d_in[8];
    const float* be2   = (const float*)d_in[9];
    const float* cbias = (const float*)d_in[10];
    const float* gamma = (const float*)d_in[11];
    const float* beta  = (const float*)d_in[12];
    (void)n_in; (void)out_size;

    int n_nodes = in_sizes[0] / DIN;   // 10000
    int n_edges = in_sizes[2];         // 100000

    char* ws = (char*)d_ws;
    size_t off = 0;
    auto carve = [&](size_t bytes) -> void* {
        void* p = ws + off;
        off = (off + bytes + 255) & ~(size_t)255;
        return p;
    };
    unsigned short* h     = (unsigned short*)carve((size_t)n_edges * EHID * 2);  // 25.6 MB
    unsigned short* msg   = (unsigned short*)carve((size_t)n_edges * 64 * 2);    // 12.8 MB (bf16)
    float*          outb  = (float*)carve((size_t)n_nodes * HDIM * 4);
    unsigned short* outbf = (unsigned short*)carve((size_t)n_nodes * HDIM * 2);
    unsigned short* BmatT = (unsigned short*)carve((size_t)TC * 64 * 2);
    int*            offS  = (int*)carve((size_t)(n_nodes + 1) * 4);
    int*            offD  = (int*)carve((size_t)(n_nodes + 1) * 4);
    int*            curS  = (int*)carve((size_t)n_nodes * 4);
    int*            curD  = (int*)carve((size_t)n_nodes * 4);
    int*            permS = (int*)carve((size_t)n_edges * 4);
    int*            rankD = (int*)carve((size_t)n_edges * 4);
    float*          stat  = (float*)carve(128 * 4 + (size_t)2 * n_nodes * 4); // stat + cntS + cntD
    int*            cntS  = (int*)(stat + 128);
    int*            cntD  = cntS + n_nodes;
    unsigned short* T     = (unsigned short*)(ws + off);
    size_t avail = ws_size > off ? ws_size - off : 0;
    long tcap = (long)(avail / ((size_t)TC * 2));   // ws-capacity bound (node rows)
    if (tcap > n_nodes) tcap = n_nodes;
    if (tcap < 64) tcap = 64;
    long tchunk = tcap;   // single chunk (chunking measured neutral)

    hipMemsetAsync(stat, 0, 128 * 4 + (size_t)2 * n_nodes * 4, stream);

    int nbN = (n_nodes + 3) / 4;            // 2500
    int nbE = (n_edges + 63) / 64;          // 1563 (MFMA edge path: 64 edges/block)
    int nbB = (TC * 64 + 255) / 256;        // 2064
    int nbH = (n_edges + 255) / 256;        // 391
    k_pro<<<dim3(nbN + nbE + nbB + nbH), 256, 0, stream>>>(
        nf, W0, b0, outb, outbf, ef, We1, be1, h, We2, be2, BmatT,
        src, dst, cntS, cntD, n_nodes, n_edges, nbN, nbE, nbB);
    k_scan<<<dim3(2), 256, 0, stream>>>(cntS, cntD, offS, offD, curS, curD, n_nodes, n_edges);
    k_perm<<<dim3((n_edges + 255) / 256), 256, 0, stream>>>(src, dst, curS, curD, permS, rankD, n_edges);

    for (int step = 0; step < STEPS; ++step) {
        for (long n0 = 0; n0 < n_nodes; n0 += tchunk) {
            long n1 = n0 + tchunk; if (n1 > n_nodes) n1 = n_nodes;
            long cnt = n1 - n0;
            k_T<<<dim3(17, (cnt + 63) / 64), 256, 0, stream>>>(
                outbf, BmatT, T, (int)n0, (int)n1);
            k_msg<<<dim3((cnt + 3) / 4), 256, 0, stream>>>(
                h, T, offS, permS, rankD, msg, (int)n0, (int)n1);
        }
        k_agg<<<dim3(n_nodes), 256, 0, stream>>>(msg, offD, cbias, outb, outbf, n_nodes);
    }

    k_bn_stats<<<dim3(64), 256, 0, stream>>>(outb, stat, n_nodes);
    k_bn_apply<<<dim3((n_nodes * HDIM + 255) / 256), 256, 0, stream>>>(
        outb, stat, gamma, beta, (float*)d_out, n_nodes * HDIM, n_nodes);
}